// Round 8
// baseline (141.623 us; speedup 1.0000x reference)
//
#include <hip/hip_runtime.h>

// C2D_34419867910289 round 8 — BT=128 via 512-thread blocks (8 waves), grid
// 1024: halves panel gload traffic per unit work (panel quarter feeds 2x
// MFMA). LDS back to r6-proven 36KB (wb[2] + sv) + two-barrier stage; per-wave
// structure identical to r6/r7 (16 b-cols/wave). vmwait<2> steady state.
// Prep kernels unchanged from r7.

typedef __attribute__((ext_vector_type(4))) float f32x4;
typedef __attribute__((ext_vector_type(8))) short bf16x8;
typedef __attribute__((ext_vector_type(4))) unsigned u32x4;

#define DEVI static __device__ __forceinline__
#define SB __builtin_amdgcn_sched_barrier(0)
#define BARR __builtin_amdgcn_s_barrier()
#define MEMF asm volatile("" ::: "memory")

constexpr int NC = 32, D = 128, C = 256, H = 256;

DEVI unsigned short f2b(float f) {  // RN-even float -> bf16 (prep)
  unsigned u = __builtin_bit_cast(unsigned, f);
  u += 0x7fffu + ((u >> 16) & 1u);
  return (unsigned short)(u >> 16);
}
DEVI float b2f(unsigned short h) {
  unsigned u = ((unsigned)h) << 16;
  return __builtin_bit_cast(float, u);
}
DEVI unsigned pk2(float a, float b) {
  return (unsigned)f2b(a) | ((unsigned)f2b(b) << 16);
}
DEVI unsigned cvtpk(float a, float b) {
  unsigned r;
  asm("v_cvt_pk_bf16_f32 %0, %1, %2" : "=v"(r) : "v"(a), "v"(b));
  return r;
}

template <int N> DEVI void vmwait() {
  asm volatile("s_waitcnt vmcnt(%0)" ::"n"(N) : "memory");
}
DEVI void lgkm0() { asm volatile("s_waitcnt lgkmcnt(0)" ::: "memory"); }

DEVI void gload16(const void* g, void* l) {
  __builtin_amdgcn_global_load_lds(
      (const __attribute__((address_space(1))) void*)g,
      (__attribute__((address_space(3))) void*)l, 16, 0, 0);
}

// Panel swizzle (8-row period): byte = row*RB + ((slot ^ (row&7))<<4) + (e&7)*2

// ---------------- prepA: K (fp32), swizzled V^T, W1t/W2t transposes --------
__global__ __launch_bounds__(256) void prepA_kernel(
    const float* __restrict__ emb, const float* __restrict__ Wk,
    const float* __restrict__ Wv, const float* __restrict__ W1,
    const float* __restrict__ W2, float* __restrict__ Ktmp,
    unsigned short* __restrict__ VtP, unsigned short* __restrict__ W1tP,
    unsigned short* __restrict__ W2tP) {
  __shared__ __align__(16) float smem[20480];  // 80KB
  const int bid = blockIdx.x, tid = threadIdx.x;
  if (bid < 512) {
    const bool isV = bid >= 256;
    const int bb = isV ? bid - 256 : bid;
    const int j = bb >> 3, ct = bb & 7;
    float* wm = smem;          // [128][128]
    float* eb = smem + 16384;  // [32][128]
    const float4* gw = (const float4*)((isV ? Wv : Wk) + (long)j * D * D);
    float4* lw = (float4*)wm;
    for (int i = tid; i < D * D / 4; i += 256) lw[i] = gw[i];
    const float4* ge = (const float4*)(emb + ((long)j * C + ct * 32) * D);
    float4* le = (float4*)eb;
    for (int i = tid; i < 32 * D / 4; i += 256) le[i] = ge[i];
    __syncthreads();
    const int e = tid & 127, h = tid >> 7;
    float acc[16];
#pragma unroll
    for (int r = 0; r < 16; ++r) acc[r] = 0.f;
    for (int d = 0; d < D; ++d) {
      float wde = wm[d * 128 + e];
#pragma unroll
      for (int r = 0; r < 16; ++r)
        acc[r] = fmaf(eb[(h * 16 + r) * 128 + d], wde, acc[r]);
    }
    if (!isV) {
      for (int r = 0; r < 16; ++r)
        Ktmp[((long)j * C + ct * 32 + h * 16 + r) * D + e] = acc[r];
    } else {
#pragma unroll
      for (int k = 0; k < 2; ++k) {
        uint4 pk = {pk2(acc[k * 8 + 0], acc[k * 8 + 1]),
                    pk2(acc[k * 8 + 2], acc[k * 8 + 3]),
                    pk2(acc[k * 8 + 4], acc[k * 8 + 5]),
                    pk2(acc[k * 8 + 6], acc[k * 8 + 7])};
        int slot = ct * 4 + h * 2 + k;
        long byte = (long)j * 65536 + e * 512 + ((slot ^ (e & 7)) << 4);
        *(uint4*)((char*)VtP + byte) = pk;
      }
    }
  } else {
    float(*t)[33] = reinterpret_cast<float(*)[33]>(smem);
    const int idx = bid - 512;
    const bool isW2 = idx >= 1024;
    const int bb = isW2 ? idx - 1024 : idx;
    const int j = bb >> 5, tile = bb & 31;
    const int rr = tid >> 3, c4 = tid & 7;
    if (!isW2) {
      const int dt = tile & 3, ht = tile >> 2;
      float4 v = *(const float4*)(W1 + ((long)j * 128 + dt * 32 + rr) * 256 + ht * 32 + c4 * 4);
      t[rr][c4 * 4 + 0] = v.x; t[rr][c4 * 4 + 1] = v.y;
      t[rr][c4 * 4 + 2] = v.z; t[rr][c4 * 4 + 3] = v.w;
      __syncthreads();
      int row = ht * 32 + rr, colb = dt * 32 + c4 * 4;
      uint2 pk = {pk2(t[c4 * 4 + 0][rr], t[c4 * 4 + 1][rr]),
                  pk2(t[c4 * 4 + 2][rr], t[c4 * 4 + 3][rr])};
      long byte = (long)j * 65536 + row * 256 + (((colb >> 3) ^ (row & 7)) << 4) + (colb & 7) * 2;
      *(uint2*)((char*)W1tP + byte) = pk;
    } else {
      const int et = tile & 3, ht = tile >> 2;
      float4 v = *(const float4*)(W2 + ((long)j * 256 + ht * 32 + rr) * 128 + et * 32 + c4 * 4);
      t[rr][c4 * 4 + 0] = v.x; t[rr][c4 * 4 + 1] = v.y;
      t[rr][c4 * 4 + 2] = v.z; t[rr][c4 * 4 + 3] = v.w;
      __syncthreads();
      int row = et * 32 + rr, colb = ht * 32 + c4 * 4;
      uint2 pk = {pk2(t[c4 * 4 + 0][rr], t[c4 * 4 + 1][rr]),
                  pk2(t[c4 * 4 + 2][rr], t[c4 * 4 + 3][rr])};
      long byte = (long)j * 65536 + row * 512 + (((colb >> 3) ^ (row & 7)) << 4) + (colb & 7) * 2;
      *(uint2*)((char*)W2tP + byte) = pk;
    }
  }
}

// ---- prepB: MtP[c][d] = (1/sqrt(D)) * sum_e Wq[d][e]K[c][e], d-split ------
__global__ __launch_bounds__(256) void prepB_kernel(
    const float* __restrict__ Wq, const float* __restrict__ Ktmp,
    unsigned short* __restrict__ MtP) {
  __shared__ float wqT[128][68];
  __shared__ float kt[32][129];
  const int bid = blockIdx.x;
  const int j = bid >> 4, ct = (bid >> 1) & 7, dh = bid & 1;
  const int tid = threadIdx.x;
  for (int i = tid; i < 64 * 32; i += 256) {
    int dloc = i >> 5, e4 = i & 31;
    float4 v = *(const float4*)(Wq + ((long)j * 128 + dh * 64 + dloc) * 128 + e4 * 4);
    wqT[e4 * 4 + 0][dloc] = v.x; wqT[e4 * 4 + 1][dloc] = v.y;
    wqT[e4 * 4 + 2][dloc] = v.z; wqT[e4 * 4 + 3][dloc] = v.w;
  }
  for (int i = tid; i < 32 * 32; i += 256) {
    int r = i >> 5, c0 = (i & 31) * 4;
    float4 v = *(const float4*)(Ktmp + ((long)j * 256 + ct * 32 + r) * 128 + c0);
    kt[r][c0 + 0] = v.x; kt[r][c0 + 1] = v.y;
    kt[r][c0 + 2] = v.z; kt[r][c0 + 3] = v.w;
  }
  __syncthreads();
  const int cl = tid >> 3, s = tid & 7;
  float acc[8];
#pragma unroll
  for (int u = 0; u < 8; ++u) acc[u] = 0.f;
  for (int e = 0; e < 128; ++e) {
    float kk = kt[cl][e];
    float4 a = *(const float4*)&wqT[e][s * 8];
    float4 b = *(const float4*)&wqT[e][s * 8 + 4];
    acc[0] = fmaf(a.x, kk, acc[0]); acc[1] = fmaf(a.y, kk, acc[1]);
    acc[2] = fmaf(a.z, kk, acc[2]); acc[3] = fmaf(a.w, kk, acc[3]);
    acc[4] = fmaf(b.x, kk, acc[4]); acc[5] = fmaf(b.y, kk, acc[5]);
    acc[6] = fmaf(b.z, kk, acc[6]); acc[7] = fmaf(b.w, kk, acc[7]);
  }
  const float scale = 0.08838834764831845f;  // 1/sqrt(128)
  int c = ct * 32 + cl;
  uint4 pk = {pk2(acc[0] * scale, acc[1] * scale),
              pk2(acc[2] * scale, acc[3] * scale),
              pk2(acc[4] * scale, acc[5] * scale),
              pk2(acc[6] * scale, acc[7] * scale)};
  int slot = dh * 8 + s;
  long byte = (long)j * 65536 + c * 256 + ((slot ^ (c & 7)) << 4);
  *(uint4*)((char*)MtP + byte) = pk;
}

// ---------------- fused main kernel (BT=128, 8 waves, 2-buffer) ------------
__global__ __launch_bounds__(512, 6) void fused_kernel(
    const float* __restrict__ x, const unsigned short* __restrict__ MtP,
    const unsigned short* __restrict__ VtP, const unsigned short* __restrict__ W1tP,
    const unsigned short* __restrict__ W2tP, const float* __restrict__ b1,
    const float* __restrict__ b2, const float* __restrict__ g1,
    const float* __restrict__ be1, const float* __restrict__ g2,
    const float* __restrict__ be2, const float* __restrict__ Ws,
    const float* __restrict__ bs, float* __restrict__ out) {
  __shared__ __align__(16) unsigned short wb[2][8192];  // 32KB
  __shared__ __align__(16) float sv[1024];              // 4KB
  const int bid = blockIdx.x;
  const int wg = (bid & 7) * 128 + (bid >> 3);  // XCD-chunked, 1024 blocks
  const int j = wg >> 5, b0 = (wg & 31) * 128;
  const int tid = threadIdx.x, w = tid >> 6, l = tid & 63, lr = l & 15, lg = l >> 4;
  const int bloc = w * 16 + lr;  // 0..127

  const unsigned short* pnl0 = MtP + (long)j * 32768;
  const unsigned short* pnl1 = VtP + (long)j * 32768;
  const unsigned short* pnl2 = W1tP + (long)j * 32768;
  const unsigned short* pnl3 = W2tP + (long)j * 32768;

  auto ISSUE = [&](int s2) {  // 2 gload_lds per wave (8 waves cover 16KB)
    const unsigned short* base = (s2 < 4) ? pnl0 : (s2 < 8) ? pnl1 : (s2 < 12) ? pnl2 : pnl3;
    const char* gq = (const char*)(base + (s2 & 3) * 8192);
    char* lb = (char*)&wb[s2 & 1][0] + w * 2048;
    SB;
#pragma unroll
    for (int t = 0; t < 2; ++t)
      gload16(gq + (w * 2 + t) * 1024 + l * 16, lb + t * 1024);
    SB;
  };

  // ---- prologue ----
  const float* xrow = x + ((long)(b0 + bloc) * NC + j) * D;
  float4 xf[4][2];
#pragma unroll
  for (int kc = 0; kc < 4; ++kc) {
    xf[kc][0] = *(const float4*)(xrow + kc * 32 + lg * 8);
    xf[kc][1] = *(const float4*)(xrow + kc * 32 + lg * 8 + 4);
  }
  for (int i = tid; i < 1024; i += 512) {
    float v;
    if (i < 256) v = b1[j * H + i];
    else if (i < 384) v = b2[j * D + i - 256];
    else if (i < 512) v = g1[i - 384];
    else if (i < 640) v = be1[i - 512];
    else if (i < 768) v = g2[i - 640];
    else if (i < 896) v = be2[i - 768];
    else v = Ws[j * D + i - 896];
    sv[i] = v;
  }
  SB;
  ISSUE(0);
  ISSUE(1);
  float bsj = bs[j];
  bf16x8 xa[4];
#pragma unroll
  for (int kc = 0; kc < 4; ++kc) {
    u32x4 t;
    t[0] = cvtpk(xf[kc][0].x, xf[kc][0].y);
    t[1] = cvtpk(xf[kc][0].z, xf[kc][0].w);
    t[2] = cvtpk(xf[kc][1].x, xf[kc][1].y);
    t[3] = cvtpk(xf[kc][1].z, xf[kc][1].w);
    xa[kc] = __builtin_bit_cast(bf16x8, t);
  }
  lgkm0(); SB; BARR; MEMF; SB;

  int inner[4], inner2[8];
#pragma unroll
  for (int kc = 0; kc < 4; ++kc)
    inner[kc] = lr * 256 + (((kc * 4 + lg) ^ (lr & 7)) << 4);
#pragma unroll
  for (int kc = 0; kc < 8; ++kc)
    inner2[kc] = lr * 512 + (((kc * 4 + lg) ^ (lr & 7)) << 4);

  const int ad0 = (((lg & 1) << 5) + lr) << 2;
  const int ad1 = ad0 + 64;
  const bool hi = (lg >> 1) != 0;

  bf16x8 aa[8], xa2[4], aa2[8];
  unsigned hb[8][2];
  float4 xr[8];

  // ---- GEMM1: S^T = Mt @ x^T (stages 0..3) ----
  f32x4 sc[16];
#pragma unroll
  for (int t = 0; t < 16; ++t) sc[t] = (f32x4){0.f, 0.f, 0.f, 0.f};
#pragma unroll
  for (int q = 0; q < 4; ++q) {
    vmwait<2>(); SB; BARR; MEMF; SB;
    const char* wp = (const char*)wb[q & 1];
    __builtin_amdgcn_s_setprio(1);
#pragma unroll
    for (int c4 = 0; c4 < 4; ++c4)
#pragma unroll
      for (int kc = 0; kc < 4; ++kc) {
        bf16x8 bf = *(const bf16x8*)(wp + c4 * 4096 + inner[kc]);
        sc[q * 4 + c4] =
            __builtin_amdgcn_mfma_f32_16x16x32_bf16(bf, xa[kc], sc[q * 4 + c4], 0, 0, 0);
      }
    __builtin_amdgcn_s_setprio(0);
    if (q == 3) {
      float mx = -1e30f;
#pragma unroll
      for (int ct = 0; ct < 16; ++ct)
#pragma unroll
        for (int i = 0; i < 4; ++i) mx = fmaxf(mx, sc[ct][i]);
      mx = fmaxf(mx, __shfl_xor(mx, 16));
      mx = fmaxf(mx, __shfl_xor(mx, 32));
      float sm = 0.f;
#pragma unroll
      for (int ct = 0; ct < 16; ++ct)
#pragma unroll
        for (int i = 0; i < 4; ++i) {
          float e = __expf(sc[ct][i] - mx);
          sc[ct][i] = e;
          sm += e;
        }
      sm += __shfl_xor(sm, 16);
      sm += __shfl_xor(sm, 32);
      float inv = 1.f / sm;
      unsigned au[16][2];
#pragma unroll
      for (int ct = 0; ct < 16; ++ct) {
        au[ct][0] = cvtpk(sc[ct][0] * inv, sc[ct][1] * inv);
        au[ct][1] = cvtpk(sc[ct][2] * inv, sc[ct][3] * inv);
      }
#pragma unroll
      for (int kc = 0; kc < 8; ++kc) {
        u32x4 t;
#pragma unroll
        for (int h = 0; h < 2; ++h) {
          int ad = h ? ad1 : ad0;
#pragma unroll
          for (int p = 0; p < 2; ++p) {
            int f0 = __builtin_amdgcn_ds_bpermute(ad, (int)au[2 * kc][p]);
            int f1 = __builtin_amdgcn_ds_bpermute(ad, (int)au[2 * kc + 1][p]);
            t[h * 2 + p] = (unsigned)(hi ? f1 : f0);
          }
        }
        aa[kc] = __builtin_bit_cast(bf16x8, t);
      }
    }
    lgkm0(); SB; BARR; MEMF; SB;
    ISSUE(q + 2);
  }

  // ---- GEMM2: h^T = V^T @ alpha^T (stages 4..7) ----
  f32x4 ha[8];
#pragma unroll
  for (int t = 0; t < 8; ++t) ha[t] = (f32x4){0.f, 0.f, 0.f, 0.f};
#pragma unroll
  for (int q = 0; q < 4; ++q) {
    if (q == 3) { vmwait<10>(); } else { vmwait<2>(); }
    SB; BARR; MEMF; SB;
    const char* wp = (const char*)wb[q & 1];
    __builtin_amdgcn_s_setprio(1);
#pragma unroll
    for (int e2 = 0; e2 < 2; ++e2)
#pragma unroll
      for (int kc = 0; kc < 8; ++kc) {
        bf16x8 bf = *(const bf16x8*)(wp + e2 * 8192 + inner2[kc]);
        ha[q * 2 + e2] =
            __builtin_amdgcn_mfma_f32_16x16x32_bf16(bf, aa[kc], ha[q * 2 + e2], 0, 0, 0);
      }
    __builtin_amdgcn_s_setprio(0);
    if (q == 2) {  // x-residual loads; drained by stage-7 vmwait<2> below
#pragma unroll
      for (int et = 0; et < 8; ++et)
        xr[et] = *(const float4*)(xrow + et * 16 + lg * 4);
    }
    if (q == 3) {
      vmwait<2>();  // xr complete (leaves ISSUE(8)'s 2 loads in flight)
      SB;
      float hvv[8][4];
      float s1 = 0.f, s2s = 0.f;
#pragma unroll
      for (int et = 0; et < 8; ++et)
#pragma unroll
        for (int i = 0; i < 4; ++i) {
          float v = ha[et][i] + xr[et][i];
          hvv[et][i] = v;
          s1 += v;
          s2s += v * v;
        }
      s1 += __shfl_xor(s1, 16); s2s += __shfl_xor(s2s, 16);
      s1 += __shfl_xor(s1, 32); s2s += __shfl_xor(s2s, 32);
      float mu = s1 * (1.f / 128.f);
      float var = s2s * (1.f / 128.f) - mu * mu;
      float rs = rsqrtf(var + 1e-5f);
#pragma unroll
      for (int et = 0; et < 8; ++et) {
        f32x4 gg = *(const f32x4*)&sv[384 + et * 16 + lg * 4];
        f32x4 bb = *(const f32x4*)&sv[512 + et * 16 + lg * 4];
        float h0 = (hvv[et][0] - mu) * rs * gg[0] + bb[0];
        float h1n = (hvv[et][1] - mu) * rs * gg[1] + bb[1];
        float h2 = (hvv[et][2] - mu) * rs * gg[2] + bb[2];
        float h3 = (hvv[et][3] - mu) * rs * gg[3] + bb[3];
        hb[et][0] = cvtpk(h0, h1n);
        hb[et][1] = cvtpk(h2, h3);
      }
#pragma unroll
      for (int kc = 0; kc < 4; ++kc) {
        u32x4 t;
#pragma unroll
        for (int h = 0; h < 2; ++h) {
          int ad = h ? ad1 : ad0;
#pragma unroll
          for (int p = 0; p < 2; ++p) {
            int f0 = __builtin_amdgcn_ds_bpermute(ad, (int)hb[2 * kc][p]);
            int f1 = __builtin_amdgcn_ds_bpermute(ad, (int)hb[2 * kc + 1][p]);
            t[h * 2 + p] = (unsigned)(hi ? f1 : f0);
          }
        }
        xa2[kc] = __builtin_bit_cast(bf16x8, t);
      }
    }
    lgkm0(); SB; BARR; MEMF; SB;
    ISSUE(6 + q);
  }

  // ---- GEMM3: ff^T = W1^T @ h1^T (stages 8..11) ----
  unsigned ffu[16][2];
#pragma unroll
  for (int q = 0; q < 4; ++q) {
    vmwait<2>(); SB; BARR; MEMF; SB;
    const char* wp = (const char*)wb[q & 1];
    f32x4 fa4[4];
#pragma unroll
    for (int t = 0; t < 4; ++t) fa4[t] = (f32x4){0.f, 0.f, 0.f, 0.f};
    __builtin_amdgcn_s_setprio(1);
#pragma unroll
    for (int c4 = 0; c4 < 4; ++c4)
#pragma unroll
      for (int kc = 0; kc < 4; ++kc) {
        bf16x8 bf = *(const bf16x8*)(wp + c4 * 4096 + inner[kc]);
        fa4[c4] =
            __builtin_amdgcn_mfma_f32_16x16x32_bf16(bf, xa2[kc], fa4[c4], 0, 0, 0);
      }
    __builtin_amdgcn_s_setprio(0);
#pragma unroll
    for (int c4 = 0; c4 < 4; ++c4) {
      int ht = q * 4 + c4;
      f32x4 bb = *(const f32x4*)&sv[ht * 16 + lg * 4];
      float v0 = fmaxf(fa4[c4][0] + bb[0], 0.f);
      float v1 = fmaxf(fa4[c4][1] + bb[1], 0.f);
      float v2 = fmaxf(fa4[c4][2] + bb[2], 0.f);
      float v3 = fmaxf(fa4[c4][3] + bb[3], 0.f);
      ffu[ht][0] = cvtpk(v0, v1);
      ffu[ht][1] = cvtpk(v2, v3);
    }
    if (q == 3) {
#pragma unroll
      for (int kc = 0; kc < 8; ++kc) {
        u32x4 t;
#pragma unroll
        for (int h = 0; h < 2; ++h) {
          int ad = h ? ad1 : ad0;
#pragma unroll
          for (int p = 0; p < 2; ++p) {
            int f0 = __builtin_amdgcn_ds_bpermute(ad, (int)ffu[2 * kc][p]);
            int f1 = __builtin_amdgcn_ds_bpermute(ad, (int)ffu[2 * kc + 1][p]);
            t[h * 2 + p] = (unsigned)(hi ? f1 : f0);
          }
        }
        aa2[kc] = __builtin_bit_cast(bf16x8, t);
      }
    }
    lgkm0(); SB; BARR; MEMF; SB;
    ISSUE(10 + q);
  }

  // ---- GEMM4: o^T = W2^T @ ff^T (stages 12..15) ----
  f32x4 oa[8];
#pragma unroll
  for (int t = 0; t < 8; ++t) oa[t] = (f32x4){0.f, 0.f, 0.f, 0.f};
#pragma unroll
  for (int q = 0; q < 4; ++q) {
    if (q == 3) { vmwait<0>(); } else { vmwait<2>(); }
    SB; BARR; MEMF; SB;
    const char* wp = (const char*)wb[q & 1];
    __builtin_amdgcn_s_setprio(1);
#pragma unroll
    for (int e2 = 0; e2 < 2; ++e2)
#pragma unroll
      for (int kc = 0; kc < 8; ++kc) {
        bf16x8 bf = *(const bf16x8*)(wp + e2 * 8192 + inner2[kc]);
        oa[q * 2 + e2] =
            __builtin_amdgcn_mfma_f32_16x16x32_bf16(bf, aa2[kc], oa[q * 2 + e2], 0, 0, 0);
      }
    __builtin_amdgcn_s_setprio(0);
    if (q < 2) {
      lgkm0(); SB; BARR; MEMF; SB;
      ISSUE(14 + q);
    }
  }
  // final epilogue: +b2 +h1(bf16), LN2, dot Ws, sigmoid
  {
    float t1 = 0.f, t2 = 0.f;
#pragma unroll
    for (int et = 0; et < 8; ++et) {
      f32x4 bb = *(const f32x4*)&sv[256 + et * 16 + lg * 4];
      float r0 = b2f((unsigned short)(hb[et][0] & 0xffff));
      float r1 = b2f((unsigned short)(hb[et][0] >> 16));
      float r2 = b2f((unsigned short)(hb[et][1] & 0xffff));
      float r3 = b2f((unsigned short)(hb[et][1] >> 16));
      float v0 = oa[et][0] + bb[0] + r0;
      float v1 = oa[et][1] + bb[1] + r1;
      float v2 = oa[et][2] + bb[2] + r2;
      float v3 = oa[et][3] + bb[3] + r3;
      oa[et][0] = v0; oa[et][1] = v1; oa[et][2] = v2; oa[et][3] = v3;
      t1 += (v0 + v1) + (v2 + v3);
      t2 += (v0 * v0 + v1 * v1) + (v2 * v2 + v3 * v3);
    }
    t1 += __shfl_xor(t1, 16); t2 += __shfl_xor(t2, 16);
    t1 += __shfl_xor(t1, 32); t2 += __shfl_xor(t2, 32);
    float mu2 = t1 * (1.f / 128.f);
    float var = t2 * (1.f / 128.f) - mu2 * mu2;
    float rs2 = rsqrtf(var + 1e-5f);
    float lp = 0.f;
#pragma unroll
    for (int et = 0; et < 8; ++et) {
      f32x4 gg = *(const f32x4*)&sv[640 + et * 16 + lg * 4];
      f32x4 bb = *(const f32x4*)&sv[768 + et * 16 + lg * 4];
      f32x4 ww = *(const f32x4*)&sv[896 + et * 16 + lg * 4];
#pragma unroll
      for (int i = 0; i < 4; ++i) {
        float h2 = (oa[et][i] - mu2) * rs2 * gg[i] + bb[i];
        lp = fmaf(h2, ww[i], lp);
      }
    }
    lp += __shfl_xor(lp, 16);
    lp += __shfl_xor(lp, 32);
    if (lg == 0) {
      float sg = 1.f / (1.f + __expf(-(lp + bsj)));
      out[(long)(b0 + bloc) * NC + j] = sg;
    }
  }
}

extern "C" void kernel_launch(void* const* d_in, const int* in_sizes, int n_in,
                              void* d_out, int out_size, void* d_ws,
                              size_t ws_size, hipStream_t stream) {
  (void)in_sizes; (void)n_in; (void)out_size; (void)ws_size;
  const float* cat = (const float*)d_in[1];
  const float* emb = (const float*)d_in[2];
  const float* Wq = (const float*)d_in[3];
  const float* Wk = (const float*)d_in[4];
  const float* Wv = (const float*)d_in[5];
  const float* g1 = (const float*)d_in[6];
  const float* be1 = (const float*)d_in[7];
  const float* W1 = (const float*)d_in[8];
  const float* b1 = (const float*)d_in[9];
  const float* W2 = (const float*)d_in[10];
  const float* b2 = (const float*)d_in[11];
  const float* g2 = (const float*)d_in[12];
  const float* be2 = (const float*)d_in[13];
  const float* Ws = (const float*)d_in[14];
  const float* bs = (const float*)d_in[15];
  float* out = (float*)d_out;

  // workspace: 12 MB
  char* ws = (char*)d_ws;
  unsigned short* MtP = (unsigned short*)(ws);              // 2 MB swz [NC][256][128]
  unsigned short* VtP = (unsigned short*)(ws + (2 << 20));  // 2 MB swz [NC][128][256]
  unsigned short* W1tP = (unsigned short*)(ws + (4 << 20)); // 2 MB swz [NC][256][128]
  unsigned short* W2tP = (unsigned short*)(ws + (6 << 20)); // 2 MB swz [NC][128][256]
  float* Ktmp = (float*)(ws + (8 << 20));                   // 4 MB [NC][256][128]

  prepA_kernel<<<2560, 256, 0, stream>>>(emb, Wk, Wv, W1, W2, Ktmp, VtP, W1tP, W2tP);
  prepB_kernel<<<512, 256, 0, stream>>>(Wq, Ktmp, MtP);
  fused_kernel<<<1024, 512, 0, stream>>>(cat, MtP, VtP, W1tP, W2tP, b1, b2, g1,
                                         be1, g2, be2, Ws, bs, out);
}

// Round 9
// 136.172 us; speedup vs baseline: 1.0400x; 1.0400x over previous
//
#include <hip/hip_runtime.h>

// C2D_34419867910289 round 9 — r8 with the launch_bounds bug fixed:
// (512,6) forced VGPR=40 -> 300MB scratch spill (WRITE_SIZE 152MB). Now
// (512,2): VGPR cap 256, per-thread ~64 VGPR + AGPR accs -> 2 blocks/CU
// (32 waves/CU). Everything else identical to r8 (BT=128, 8 waves, 2-buffer,
// vmwait<2> steady state; prep kernels unchanged from r7).

typedef __attribute__((ext_vector_type(4))) float f32x4;
typedef __attribute__((ext_vector_type(8))) short bf16x8;
typedef __attribute__((ext_vector_type(4))) unsigned u32x4;

#define DEVI static __device__ __forceinline__
#define SB __builtin_amdgcn_sched_barrier(0)
#define BARR __builtin_amdgcn_s_barrier()
#define MEMF asm volatile("" ::: "memory")

constexpr int NC = 32, D = 128, C = 256, H = 256;

DEVI unsigned short f2b(float f) {  // RN-even float -> bf16 (prep)
  unsigned u = __builtin_bit_cast(unsigned, f);
  u += 0x7fffu + ((u >> 16) & 1u);
  return (unsigned short)(u >> 16);
}
DEVI float b2f(unsigned short h) {
  unsigned u = ((unsigned)h) << 16;
  return __builtin_bit_cast(float, u);
}
DEVI unsigned pk2(float a, float b) {
  return (unsigned)f2b(a) | ((unsigned)f2b(b) << 16);
}
DEVI unsigned cvtpk(float a, float b) {
  unsigned r;
  asm("v_cvt_pk_bf16_f32 %0, %1, %2" : "=v"(r) : "v"(a), "v"(b));
  return r;
}

template <int N> DEVI void vmwait() {
  asm volatile("s_waitcnt vmcnt(%0)" ::"n"(N) : "memory");
}
DEVI void lgkm0() { asm volatile("s_waitcnt lgkmcnt(0)" ::: "memory"); }

DEVI void gload16(const void* g, void* l) {
  __builtin_amdgcn_global_load_lds(
      (const __attribute__((address_space(1))) void*)g,
      (__attribute__((address_space(3))) void*)l, 16, 0, 0);
}

// Panel swizzle (8-row period): byte = row*RB + ((slot ^ (row&7))<<4) + (e&7)*2

// ---------------- prepA: K (fp32), swizzled V^T, W1t/W2t transposes --------
__global__ __launch_bounds__(256) void prepA_kernel(
    const float* __restrict__ emb, const float* __restrict__ Wk,
    const float* __restrict__ Wv, const float* __restrict__ W1,
    const float* __restrict__ W2, float* __restrict__ Ktmp,
    unsigned short* __restrict__ VtP, unsigned short* __restrict__ W1tP,
    unsigned short* __restrict__ W2tP) {
  __shared__ __align__(16) float smem[20480];  // 80KB
  const int bid = blockIdx.x, tid = threadIdx.x;
  if (bid < 512) {
    const bool isV = bid >= 256;
    const int bb = isV ? bid - 256 : bid;
    const int j = bb >> 3, ct = bb & 7;
    float* wm = smem;          // [128][128]
    float* eb = smem + 16384;  // [32][128]
    const float4* gw = (const float4*)((isV ? Wv : Wk) + (long)j * D * D);
    float4* lw = (float4*)wm;
    for (int i = tid; i < D * D / 4; i += 256) lw[i] = gw[i];
    const float4* ge = (const float4*)(emb + ((long)j * C + ct * 32) * D);
    float4* le = (float4*)eb;
    for (int i = tid; i < 32 * D / 4; i += 256) le[i] = ge[i];
    __syncthreads();
    const int e = tid & 127, h = tid >> 7;
    float acc[16];
#pragma unroll
    for (int r = 0; r < 16; ++r) acc[r] = 0.f;
    for (int d = 0; d < D; ++d) {
      float wde = wm[d * 128 + e];
#pragma unroll
      for (int r = 0; r < 16; ++r)
        acc[r] = fmaf(eb[(h * 16 + r) * 128 + d], wde, acc[r]);
    }
    if (!isV) {
      for (int r = 0; r < 16; ++r)
        Ktmp[((long)j * C + ct * 32 + h * 16 + r) * D + e] = acc[r];
    } else {
#pragma unroll
      for (int k = 0; k < 2; ++k) {
        uint4 pk = {pk2(acc[k * 8 + 0], acc[k * 8 + 1]),
                    pk2(acc[k * 8 + 2], acc[k * 8 + 3]),
                    pk2(acc[k * 8 + 4], acc[k * 8 + 5]),
                    pk2(acc[k * 8 + 6], acc[k * 8 + 7])};
        int slot = ct * 4 + h * 2 + k;
        long byte = (long)j * 65536 + e * 512 + ((slot ^ (e & 7)) << 4);
        *(uint4*)((char*)VtP + byte) = pk;
      }
    }
  } else {
    float(*t)[33] = reinterpret_cast<float(*)[33]>(smem);
    const int idx = bid - 512;
    const bool isW2 = idx >= 1024;
    const int bb = isW2 ? idx - 1024 : idx;
    const int j = bb >> 5, tile = bb & 31;
    const int rr = tid >> 3, c4 = tid & 7;
    if (!isW2) {
      const int dt = tile & 3, ht = tile >> 2;
      float4 v = *(const float4*)(W1 + ((long)j * 128 + dt * 32 + rr) * 256 + ht * 32 + c4 * 4);
      t[rr][c4 * 4 + 0] = v.x; t[rr][c4 * 4 + 1] = v.y;
      t[rr][c4 * 4 + 2] = v.z; t[rr][c4 * 4 + 3] = v.w;
      __syncthreads();
      int row = ht * 32 + rr, colb = dt * 32 + c4 * 4;
      uint2 pk = {pk2(t[c4 * 4 + 0][rr], t[c4 * 4 + 1][rr]),
                  pk2(t[c4 * 4 + 2][rr], t[c4 * 4 + 3][rr])};
      long byte = (long)j * 65536 + row * 256 + (((colb >> 3) ^ (row & 7)) << 4) + (colb & 7) * 2;
      *(uint2*)((char*)W1tP + byte) = pk;
    } else {
      const int et = tile & 3, ht = tile >> 2;
      float4 v = *(const float4*)(W2 + ((long)j * 256 + ht * 32 + rr) * 128 + et * 32 + c4 * 4);
      t[rr][c4 * 4 + 0] = v.x; t[rr][c4 * 4 + 1] = v.y;
      t[rr][c4 * 4 + 2] = v.z; t[rr][c4 * 4 + 3] = v.w;
      __syncthreads();
      int row = et * 32 + rr, colb = ht * 32 + c4 * 4;
      uint2 pk = {pk2(t[c4 * 4 + 0][rr], t[c4 * 4 + 1][rr]),
                  pk2(t[c4 * 4 + 2][rr], t[c4 * 4 + 3][rr])};
      long byte = (long)j * 65536 + row * 512 + (((colb >> 3) ^ (row & 7)) << 4) + (colb & 7) * 2;
      *(uint2*)((char*)W2tP + byte) = pk;
    }
  }
}

// ---- prepB: MtP[c][d] = (1/sqrt(D)) * sum_e Wq[d][e]K[c][e], d-split ------
__global__ __launch_bounds__(256) void prepB_kernel(
    const float* __restrict__ Wq, const float* __restrict__ Ktmp,
    unsigned short* __restrict__ MtP) {
  __shared__ float wqT[128][68];
  __shared__ float kt[32][129];
  const int bid = blockIdx.x;
  const int j = bid >> 4, ct = (bid >> 1) & 7, dh = bid & 1;
  const int tid = threadIdx.x;
  for (int i = tid; i < 64 * 32; i += 256) {
    int dloc = i >> 5, e4 = i & 31;
    float4 v = *(const float4*)(Wq + ((long)j * 128 + dh * 64 + dloc) * 128 + e4 * 4);
    wqT[e4 * 4 + 0][dloc] = v.x; wqT[e4 * 4 + 1][dloc] = v.y;
    wqT[e4 * 4 + 2][dloc] = v.z; wqT[e4 * 4 + 3][dloc] = v.w;
  }
  for (int i = tid; i < 32 * 32; i += 256) {
    int r = i >> 5, c0 = (i & 31) * 4;
    float4 v = *(const float4*)(Ktmp + ((long)j * 256 + ct * 32 + r) * 128 + c0);
    kt[r][c0 + 0] = v.x; kt[r][c0 + 1] = v.y;
    kt[r][c0 + 2] = v.z; kt[r][c0 + 3] = v.w;
  }
  __syncthreads();
  const int cl = tid >> 3, s = tid & 7;
  float acc[8];
#pragma unroll
  for (int u = 0; u < 8; ++u) acc[u] = 0.f;
  for (int e = 0; e < 128; ++e) {
    float kk = kt[cl][e];
    float4 a = *(const float4*)&wqT[e][s * 8];
    float4 b = *(const float4*)&wqT[e][s * 8 + 4];
    acc[0] = fmaf(a.x, kk, acc[0]); acc[1] = fmaf(a.y, kk, acc[1]);
    acc[2] = fmaf(a.z, kk, acc[2]); acc[3] = fmaf(a.w, kk, acc[3]);
    acc[4] = fmaf(b.x, kk, acc[4]); acc[5] = fmaf(b.y, kk, acc[5]);
    acc[6] = fmaf(b.z, kk, acc[6]); acc[7] = fmaf(b.w, kk, acc[7]);
  }
  const float scale = 0.08838834764831845f;  // 1/sqrt(128)
  int c = ct * 32 + cl;
  uint4 pk = {pk2(acc[0] * scale, acc[1] * scale),
              pk2(acc[2] * scale, acc[3] * scale),
              pk2(acc[4] * scale, acc[5] * scale),
              pk2(acc[6] * scale, acc[7] * scale)};
  int slot = dh * 8 + s;
  long byte = (long)j * 65536 + c * 256 + ((slot ^ (c & 7)) << 4);
  *(uint4*)((char*)MtP + byte) = pk;
}

// ---------------- fused main kernel (BT=128, 8 waves, 2-buffer) ------------
__global__ __launch_bounds__(512, 2) void fused_kernel(
    const float* __restrict__ x, const unsigned short* __restrict__ MtP,
    const unsigned short* __restrict__ VtP, const unsigned short* __restrict__ W1tP,
    const unsigned short* __restrict__ W2tP, const float* __restrict__ b1,
    const float* __restrict__ b2, const float* __restrict__ g1,
    const float* __restrict__ be1, const float* __restrict__ g2,
    const float* __restrict__ be2, const float* __restrict__ Ws,
    const float* __restrict__ bs, float* __restrict__ out) {
  __shared__ __align__(16) unsigned short wb[2][8192];  // 32KB
  __shared__ __align__(16) float sv[1024];              // 4KB
  const int bid = blockIdx.x;
  const int wg = (bid & 7) * 128 + (bid >> 3);  // XCD-chunked, 1024 blocks
  const int j = wg >> 5, b0 = (wg & 31) * 128;
  const int tid = threadIdx.x, w = tid >> 6, l = tid & 63, lr = l & 15, lg = l >> 4;
  const int bloc = w * 16 + lr;  // 0..127

  const unsigned short* pnl0 = MtP + (long)j * 32768;
  const unsigned short* pnl1 = VtP + (long)j * 32768;
  const unsigned short* pnl2 = W1tP + (long)j * 32768;
  const unsigned short* pnl3 = W2tP + (long)j * 32768;

  auto ISSUE = [&](int s2) {  // 2 gload_lds per wave (8 waves cover 16KB)
    const unsigned short* base = (s2 < 4) ? pnl0 : (s2 < 8) ? pnl1 : (s2 < 12) ? pnl2 : pnl3;
    const char* gq = (const char*)(base + (s2 & 3) * 8192);
    char* lb = (char*)&wb[s2 & 1][0] + w * 2048;
    SB;
#pragma unroll
    for (int t = 0; t < 2; ++t)
      gload16(gq + (w * 2 + t) * 1024 + l * 16, lb + t * 1024);
    SB;
  };

  // ---- prologue ----
  const float* xrow = x + ((long)(b0 + bloc) * NC + j) * D;
  float4 xf[4][2];
#pragma unroll
  for (int kc = 0; kc < 4; ++kc) {
    xf[kc][0] = *(const float4*)(xrow + kc * 32 + lg * 8);
    xf[kc][1] = *(const float4*)(xrow + kc * 32 + lg * 8 + 4);
  }
  for (int i = tid; i < 1024; i += 512) {
    float v;
    if (i < 256) v = b1[j * H + i];
    else if (i < 384) v = b2[j * D + i - 256];
    else if (i < 512) v = g1[i - 384];
    else if (i < 640) v = be1[i - 512];
    else if (i < 768) v = g2[i - 640];
    else if (i < 896) v = be2[i - 768];
    else v = Ws[j * D + i - 896];
    sv[i] = v;
  }
  SB;
  ISSUE(0);
  ISSUE(1);
  float bsj = bs[j];
  bf16x8 xa[4];
#pragma unroll
  for (int kc = 0; kc < 4; ++kc) {
    u32x4 t;
    t[0] = cvtpk(xf[kc][0].x, xf[kc][0].y);
    t[1] = cvtpk(xf[kc][0].z, xf[kc][0].w);
    t[2] = cvtpk(xf[kc][1].x, xf[kc][1].y);
    t[3] = cvtpk(xf[kc][1].z, xf[kc][1].w);
    xa[kc] = __builtin_bit_cast(bf16x8, t);
  }
  lgkm0(); SB; BARR; MEMF; SB;

  int inner[4], inner2[8];
#pragma unroll
  for (int kc = 0; kc < 4; ++kc)
    inner[kc] = lr * 256 + (((kc * 4 + lg) ^ (lr & 7)) << 4);
#pragma unroll
  for (int kc = 0; kc < 8; ++kc)
    inner2[kc] = lr * 512 + (((kc * 4 + lg) ^ (lr & 7)) << 4);

  const int ad0 = (((lg & 1) << 5) + lr) << 2;
  const int ad1 = ad0 + 64;
  const bool hi = (lg >> 1) != 0;

  bf16x8 aa[8], xa2[4], aa2[8];
  unsigned hb[8][2];
  float4 xr[8];

  // ---- GEMM1: S^T = Mt @ x^T (stages 0..3) ----
  f32x4 sc[16];
#pragma unroll
  for (int t = 0; t < 16; ++t) sc[t] = (f32x4){0.f, 0.f, 0.f, 0.f};
#pragma unroll
  for (int q = 0; q < 4; ++q) {
    vmwait<2>(); SB; BARR; MEMF; SB;
    const char* wp = (const char*)wb[q & 1];
    __builtin_amdgcn_s_setprio(1);
#pragma unroll
    for (int c4 = 0; c4 < 4; ++c4)
#pragma unroll
      for (int kc = 0; kc < 4; ++kc) {
        bf16x8 bf = *(const bf16x8*)(wp + c4 * 4096 + inner[kc]);
        sc[q * 4 + c4] =
            __builtin_amdgcn_mfma_f32_16x16x32_bf16(bf, xa[kc], sc[q * 4 + c4], 0, 0, 0);
      }
    __builtin_amdgcn_s_setprio(0);
    if (q == 3) {
      float mx = -1e30f;
#pragma unroll
      for (int ct = 0; ct < 16; ++ct)
#pragma unroll
        for (int i = 0; i < 4; ++i) mx = fmaxf(mx, sc[ct][i]);
      mx = fmaxf(mx, __shfl_xor(mx, 16));
      mx = fmaxf(mx, __shfl_xor(mx, 32));
      float sm = 0.f;
#pragma unroll
      for (int ct = 0; ct < 16; ++ct)
#pragma unroll
        for (int i = 0; i < 4; ++i) {
          float e = __expf(sc[ct][i] - mx);
          sc[ct][i] = e;
          sm += e;
        }
      sm += __shfl_xor(sm, 16);
      sm += __shfl_xor(sm, 32);
      float inv = 1.f / sm;
      unsigned au[16][2];
#pragma unroll
      for (int ct = 0; ct < 16; ++ct) {
        au[ct][0] = cvtpk(sc[ct][0] * inv, sc[ct][1] * inv);
        au[ct][1] = cvtpk(sc[ct][2] * inv, sc[ct][3] * inv);
      }
#pragma unroll
      for (int kc = 0; kc < 8; ++kc) {
        u32x4 t;
#pragma unroll
        for (int h = 0; h < 2; ++h) {
          int ad = h ? ad1 : ad0;
#pragma unroll
          for (int p = 0; p < 2; ++p) {
            int f0 = __builtin_amdgcn_ds_bpermute(ad, (int)au[2 * kc][p]);
            int f1 = __builtin_amdgcn_ds_bpermute(ad, (int)au[2 * kc + 1][p]);
            t[h * 2 + p] = (unsigned)(hi ? f1 : f0);
          }
        }
        aa[kc] = __builtin_bit_cast(bf16x8, t);
      }
    }
    lgkm0(); SB; BARR; MEMF; SB;
    ISSUE(q + 2);
  }

  // ---- GEMM2: h^T = V^T @ alpha^T (stages 4..7) ----
  f32x4 ha[8];
#pragma unroll
  for (int t = 0; t < 8; ++t) ha[t] = (f32x4){0.f, 0.f, 0.f, 0.f};
#pragma unroll
  for (int q = 0; q < 4; ++q) {
    if (q == 3) { vmwait<10>(); } else { vmwait<2>(); }
    SB; BARR; MEMF; SB;
    const char* wp = (const char*)wb[q & 1];
    __builtin_amdgcn_s_setprio(1);
#pragma unroll
    for (int e2 = 0; e2 < 2; ++e2)
#pragma unroll
      for (int kc = 0; kc < 8; ++kc) {
        bf16x8 bf = *(const bf16x8*)(wp + e2 * 8192 + inner2[kc]);
        ha[q * 2 + e2] =
            __builtin_amdgcn_mfma_f32_16x16x32_bf16(bf, aa[kc], ha[q * 2 + e2], 0, 0, 0);
      }
    __builtin_amdgcn_s_setprio(0);
    if (q == 2) {  // x-residual loads; drained by stage-7 vmwait<2> below
#pragma unroll
      for (int et = 0; et < 8; ++et)
        xr[et] = *(const float4*)(xrow + et * 16 + lg * 4);
    }
    if (q == 3) {
      vmwait<2>();  // xr complete (leaves ISSUE(8)'s 2 loads in flight)
      SB;
      float hvv[8][4];
      float s1 = 0.f, s2s = 0.f;
#pragma unroll
      for (int et = 0; et < 8; ++et)
#pragma unroll
        for (int i = 0; i < 4; ++i) {
          float v = ha[et][i] + xr[et][i];
          hvv[et][i] = v;
          s1 += v;
          s2s += v * v;
        }
      s1 += __shfl_xor(s1, 16); s2s += __shfl_xor(s2s, 16);
      s1 += __shfl_xor(s1, 32); s2s += __shfl_xor(s2s, 32);
      float mu = s1 * (1.f / 128.f);
      float var = s2s * (1.f / 128.f) - mu * mu;
      float rs = rsqrtf(var + 1e-5f);
#pragma unroll
      for (int et = 0; et < 8; ++et) {
        f32x4 gg = *(const f32x4*)&sv[384 + et * 16 + lg * 4];
        f32x4 bb = *(const f32x4*)&sv[512 + et * 16 + lg * 4];
        float h0 = (hvv[et][0] - mu) * rs * gg[0] + bb[0];
        float h1n = (hvv[et][1] - mu) * rs * gg[1] + bb[1];
        float h2 = (hvv[et][2] - mu) * rs * gg[2] + bb[2];
        float h3 = (hvv[et][3] - mu) * rs * gg[3] + bb[3];
        hb[et][0] = cvtpk(h0, h1n);
        hb[et][1] = cvtpk(h2, h3);
      }
#pragma unroll
      for (int kc = 0; kc < 4; ++kc) {
        u32x4 t;
#pragma unroll
        for (int h = 0; h < 2; ++h) {
          int ad = h ? ad1 : ad0;
#pragma unroll
          for (int p = 0; p < 2; ++p) {
            int f0 = __builtin_amdgcn_ds_bpermute(ad, (int)hb[2 * kc][p]);
            int f1 = __builtin_amdgcn_ds_bpermute(ad, (int)hb[2 * kc + 1][p]);
            t[h * 2 + p] = (unsigned)(hi ? f1 : f0);
          }
        }
        xa2[kc] = __builtin_bit_cast(bf16x8, t);
      }
    }
    lgkm0(); SB; BARR; MEMF; SB;
    ISSUE(6 + q);
  }

  // ---- GEMM3: ff^T = W1^T @ h1^T (stages 8..11) ----
  unsigned ffu[16][2];
#pragma unroll
  for (int q = 0; q < 4; ++q) {
    vmwait<2>(); SB; BARR; MEMF; SB;
    const char* wp = (const char*)wb[q & 1];
    f32x4 fa4[4];
#pragma unroll
    for (int t = 0; t < 4; ++t) fa4[t] = (f32x4){0.f, 0.f, 0.f, 0.f};
    __builtin_amdgcn_s_setprio(1);
#pragma unroll
    for (int c4 = 0; c4 < 4; ++c4)
#pragma unroll
      for (int kc = 0; kc < 4; ++kc) {
        bf16x8 bf = *(const bf16x8*)(wp + c4 * 4096 + inner[kc]);
        fa4[c4] =
            __builtin_amdgcn_mfma_f32_16x16x32_bf16(bf, xa2[kc], fa4[c4], 0, 0, 0);
      }
    __builtin_amdgcn_s_setprio(0);
#pragma unroll
    for (int c4 = 0; c4 < 4; ++c4) {
      int ht = q * 4 + c4;
      f32x4 bb = *(const f32x4*)&sv[ht * 16 + lg * 4];
      float v0 = fmaxf(fa4[c4][0] + bb[0], 0.f);
      float v1 = fmaxf(fa4[c4][1] + bb[1], 0.f);
      float v2 = fmaxf(fa4[c4][2] + bb[2], 0.f);
      float v3 = fmaxf(fa4[c4][3] + bb[3], 0.f);
      ffu[ht][0] = cvtpk(v0, v1);
      ffu[ht][1] = cvtpk(v2, v3);
    }
    if (q == 3) {
#pragma unroll
      for (int kc = 0; kc < 8; ++kc) {
        u32x4 t;
#pragma unroll
        for (int h = 0; h < 2; ++h) {
          int ad = h ? ad1 : ad0;
#pragma unroll
          for (int p = 0; p < 2; ++p) {
            int f0 = __builtin_amdgcn_ds_bpermute(ad, (int)ffu[2 * kc][p]);
            int f1 = __builtin_amdgcn_ds_bpermute(ad, (int)ffu[2 * kc + 1][p]);
            t[h * 2 + p] = (unsigned)(hi ? f1 : f0);
          }
        }
        aa2[kc] = __builtin_bit_cast(bf16x8, t);
      }
    }
    lgkm0(); SB; BARR; MEMF; SB;
    ISSUE(10 + q);
  }

  // ---- GEMM4: o^T = W2^T @ ff^T (stages 12..15) ----
  f32x4 oa[8];
#pragma unroll
  for (int t = 0; t < 8; ++t) oa[t] = (f32x4){0.f, 0.f, 0.f, 0.f};
#pragma unroll
  for (int q = 0; q < 4; ++q) {
    if (q == 3) { vmwait<0>(); } else { vmwait<2>(); }
    SB; BARR; MEMF; SB;
    const char* wp = (const char*)wb[q & 1];
    __builtin_amdgcn_s_setprio(1);
#pragma unroll
    for (int e2 = 0; e2 < 2; ++e2)
#pragma unroll
      for (int kc = 0; kc < 8; ++kc) {
        bf16x8 bf = *(const bf16x8*)(wp + e2 * 8192 + inner2[kc]);
        oa[q * 2 + e2] =
            __builtin_amdgcn_mfma_f32_16x16x32_bf16(bf, aa2[kc], oa[q * 2 + e2], 0, 0, 0);
      }
    __builtin_amdgcn_s_setprio(0);
    if (q < 2) {
      lgkm0(); SB; BARR; MEMF; SB;
      ISSUE(14 + q);
    }
  }
  // final epilogue: +b2 +h1(bf16), LN2, dot Ws, sigmoid
  {
    float t1 = 0.f, t2 = 0.f;
#pragma unroll
    for (int et = 0; et < 8; ++et) {
      f32x4 bb = *(const f32x4*)&sv[256 + et * 16 + lg * 4];
      float r0 = b2f((unsigned short)(hb[et][0] & 0xffff));
      float r1 = b2f((unsigned short)(hb[et][0] >> 16));
      float r2 = b2f((unsigned short)(hb[et][1] & 0xffff));
      float r3 = b2f((unsigned short)(hb[et][1] >> 16));
      float v0 = oa[et][0] + bb[0] + r0;
      float v1 = oa[et][1] + bb[1] + r1;
      float v2 = oa[et][2] + bb[2] + r2;
      float v3 = oa[et][3] + bb[3] + r3;
      oa[et][0] = v0; oa[et][1] = v1; oa[et][2] = v2; oa[et][3] = v3;
      t1 += (v0 + v1) + (v2 + v3);
      t2 += (v0 * v0 + v1 * v1) + (v2 * v2 + v3 * v3);
    }
    t1 += __shfl_xor(t1, 16); t2 += __shfl_xor(t2, 16);
    t1 += __shfl_xor(t1, 32); t2 += __shfl_xor(t2, 32);
    float mu2 = t1 * (1.f / 128.f);
    float var = t2 * (1.f / 128.f) - mu2 * mu2;
    float rs2 = rsqrtf(var + 1e-5f);
    float lp = 0.f;
#pragma unroll
    for (int et = 0; et < 8; ++et) {
      f32x4 gg = *(const f32x4*)&sv[640 + et * 16 + lg * 4];
      f32x4 bb = *(const f32x4*)&sv[768 + et * 16 + lg * 4];
      f32x4 ww = *(const f32x4*)&sv[896 + et * 16 + lg * 4];
#pragma unroll
      for (int i = 0; i < 4; ++i) {
        float h2 = (oa[et][i] - mu2) * rs2 * gg[i] + bb[i];
        lp = fmaf(h2, ww[i], lp);
      }
    }
    lp += __shfl_xor(lp, 16);
    lp += __shfl_xor(lp, 32);
    if (lg == 0) {
      float sg = 1.f / (1.f + __expf(-(lp + bsj)));
      out[(long)(b0 + bloc) * NC + j] = sg;
    }
  }
}

extern "C" void kernel_launch(void* const* d_in, const int* in_sizes, int n_in,
                              void* d_out, int out_size, void* d_ws,
                              size_t ws_size, hipStream_t stream) {
  (void)in_sizes; (void)n_in; (void)out_size; (void)ws_size;
  const float* cat = (const float*)d_in[1];
  const float* emb = (const float*)d_in[2];
  const float* Wq = (const float*)d_in[3];
  const float* Wk = (const float*)d_in[4];
  const float* Wv = (const float*)d_in[5];
  const float* g1 = (const float*)d_in[6];
  const float* be1 = (const float*)d_in[7];
  const float* W1 = (const float*)d_in[8];
  const float* b1 = (const float*)d_in[9];
  const float* W2 = (const float*)d_in[10];
  const float* b2 = (const float*)d_in[11];
  const float* g2 = (const float*)d_in[12];
  const float* be2 = (const float*)d_in[13];
  const float* Ws = (const float*)d_in[14];
  const float* bs = (const float*)d_in[15];
  float* out = (float*)d_out;

  // workspace: 12 MB
  char* ws = (char*)d_ws;
  unsigned short* MtP = (unsigned short*)(ws);              // 2 MB swz [NC][256][128]
  unsigned short* VtP = (unsigned short*)(ws + (2 << 20));  // 2 MB swz [NC][128][256]
  unsigned short* W1tP = (unsigned short*)(ws + (4 << 20)); // 2 MB swz [NC][256][128]
  unsigned short* W2tP = (unsigned short*)(ws + (6 << 20)); // 2 MB swz [NC][128][256]
  float* Ktmp = (float*)(ws + (8 << 20));                   // 4 MB [NC][256][128]

  prepA_kernel<<<2560, 256, 0, stream>>>(emb, Wk, Wv, W1, W2, Ktmp, VtP, W1tP, W2tP);
  prepB_kernel<<<512, 256, 0, stream>>>(Wq, Ktmp, MtP);
  fused_kernel<<<1024, 512, 0, stream>>>(cat, MtP, VtP, W1tP, W2tP, b1, b2, g1,
                                         be1, g2, be2, Ws, bs, out);
}

// Round 10
// 114.349 us; speedup vs baseline: 1.2385x; 1.1908x over previous
//
#include <hip/hip_runtime.h>

// C2D_34419867910289 round 10 — recombination of proven optima:
// fused = r6 verbatim (BT=64, 256thr/4 waves, 36KB LDS -> 4 blocks/CU; best
// measured fused at 86us; occupancy is register-capped: 64 VGPR + 64 AGPR
// acc = 128/wave -> 16 waves/CU), preps = r7 verbatim (prepA merged kv+tr,
// prepB d-split; ~24us). r8/r9 refuted the VMEM-delivery theory (FETCH
// halved, time up) -> serialization-bound; block concurrency is the lever.

typedef __attribute__((ext_vector_type(4))) float f32x4;
typedef __attribute__((ext_vector_type(8))) short bf16x8;
typedef __attribute__((ext_vector_type(4))) unsigned u32x4;

#define DEVI static __device__ __forceinline__
#define SB __builtin_amdgcn_sched_barrier(0)
#define BARR __builtin_amdgcn_s_barrier()
#define MEMF asm volatile("" ::: "memory")

constexpr int NC = 32, D = 128, C = 256, H = 256;

DEVI unsigned short f2b(float f) {  // RN-even float -> bf16 (prep)
  unsigned u = __builtin_bit_cast(unsigned, f);
  u += 0x7fffu + ((u >> 16) & 1u);
  return (unsigned short)(u >> 16);
}
DEVI float b2f(unsigned short h) {
  unsigned u = ((unsigned)h) << 16;
  return __builtin_bit_cast(float, u);
}
DEVI unsigned pk2(float a, float b) {
  return (unsigned)f2b(a) | ((unsigned)f2b(b) << 16);
}
DEVI unsigned cvtpk(float a, float b) {
  unsigned r;
  asm("v_cvt_pk_bf16_f32 %0, %1, %2" : "=v"(r) : "v"(a), "v"(b));
  return r;
}

template <int N> DEVI void vmwait() {
  asm volatile("s_waitcnt vmcnt(%0)" ::"n"(N) : "memory");
}
DEVI void lgkm0() { asm volatile("s_waitcnt lgkmcnt(0)" ::: "memory"); }

DEVI void gload16(const void* g, void* l) {
  __builtin_amdgcn_global_load_lds(
      (const __attribute__((address_space(1))) void*)g,
      (__attribute__((address_space(3))) void*)l, 16, 0, 0);
}

// Panel swizzle (8-row period): byte = row*RB + ((slot ^ (row&7))<<4) + (e&7)*2

// ---------------- prepA: K (fp32), swizzled V^T, W1t/W2t transposes --------
__global__ __launch_bounds__(256) void prepA_kernel(
    const float* __restrict__ emb, const float* __restrict__ Wk,
    const float* __restrict__ Wv, const float* __restrict__ W1,
    const float* __restrict__ W2, float* __restrict__ Ktmp,
    unsigned short* __restrict__ VtP, unsigned short* __restrict__ W1tP,
    unsigned short* __restrict__ W2tP) {
  __shared__ __align__(16) float smem[20480];  // 80KB
  const int bid = blockIdx.x, tid = threadIdx.x;
  if (bid < 512) {
    const bool isV = bid >= 256;
    const int bb = isV ? bid - 256 : bid;
    const int j = bb >> 3, ct = bb & 7;
    float* wm = smem;          // [128][128]
    float* eb = smem + 16384;  // [32][128]
    const float4* gw = (const float4*)((isV ? Wv : Wk) + (long)j * D * D);
    float4* lw = (float4*)wm;
    for (int i = tid; i < D * D / 4; i += 256) lw[i] = gw[i];
    const float4* ge = (const float4*)(emb + ((long)j * C + ct * 32) * D);
    float4* le = (float4*)eb;
    for (int i = tid; i < 32 * D / 4; i += 256) le[i] = ge[i];
    __syncthreads();
    const int e = tid & 127, h = tid >> 7;
    float acc[16];
#pragma unroll
    for (int r = 0; r < 16; ++r) acc[r] = 0.f;
    for (int d = 0; d < D; ++d) {
      float wde = wm[d * 128 + e];
#pragma unroll
      for (int r = 0; r < 16; ++r)
        acc[r] = fmaf(eb[(h * 16 + r) * 128 + d], wde, acc[r]);
    }
    if (!isV) {
      for (int r = 0; r < 16; ++r)
        Ktmp[((long)j * C + ct * 32 + h * 16 + r) * D + e] = acc[r];
    } else {
#pragma unroll
      for (int k = 0; k < 2; ++k) {
        uint4 pk = {pk2(acc[k * 8 + 0], acc[k * 8 + 1]),
                    pk2(acc[k * 8 + 2], acc[k * 8 + 3]),
                    pk2(acc[k * 8 + 4], acc[k * 8 + 5]),
                    pk2(acc[k * 8 + 6], acc[k * 8 + 7])};
        int slot = ct * 4 + h * 2 + k;
        long byte = (long)j * 65536 + e * 512 + ((slot ^ (e & 7)) << 4);
        *(uint4*)((char*)VtP + byte) = pk;
      }
    }
  } else {
    float(*t)[33] = reinterpret_cast<float(*)[33]>(smem);
    const int idx = bid - 512;
    const bool isW2 = idx >= 1024;
    const int bb = isW2 ? idx - 1024 : idx;
    const int j = bb >> 5, tile = bb & 31;
    const int rr = tid >> 3, c4 = tid & 7;
    if (!isW2) {
      const int dt = tile & 3, ht = tile >> 2;
      float4 v = *(const float4*)(W1 + ((long)j * 128 + dt * 32 + rr) * 256 + ht * 32 + c4 * 4);
      t[rr][c4 * 4 + 0] = v.x; t[rr][c4 * 4 + 1] = v.y;
      t[rr][c4 * 4 + 2] = v.z; t[rr][c4 * 4 + 3] = v.w;
      __syncthreads();
      int row = ht * 32 + rr, colb = dt * 32 + c4 * 4;
      uint2 pk = {pk2(t[c4 * 4 + 0][rr], t[c4 * 4 + 1][rr]),
                  pk2(t[c4 * 4 + 2][rr], t[c4 * 4 + 3][rr])};
      long byte = (long)j * 65536 + row * 256 + (((colb >> 3) ^ (row & 7)) << 4) + (colb & 7) * 2;
      *(uint2*)((char*)W1tP + byte) = pk;
    } else {
      const int et = tile & 3, ht = tile >> 2;
      float4 v = *(const float4*)(W2 + ((long)j * 256 + ht * 32 + rr) * 128 + et * 32 + c4 * 4);
      t[rr][c4 * 4 + 0] = v.x; t[rr][c4 * 4 + 1] = v.y;
      t[rr][c4 * 4 + 2] = v.z; t[rr][c4 * 4 + 3] = v.w;
      __syncthreads();
      int row = et * 32 + rr, colb = ht * 32 + c4 * 4;
      uint2 pk = {pk2(t[c4 * 4 + 0][rr], t[c4 * 4 + 1][rr]),
                  pk2(t[c4 * 4 + 2][rr], t[c4 * 4 + 3][rr])};
      long byte = (long)j * 65536 + row * 512 + (((colb >> 3) ^ (row & 7)) << 4) + (colb & 7) * 2;
      *(uint2*)((char*)W2tP + byte) = pk;
    }
  }
}

// ---- prepB: MtP[c][d] = (1/sqrt(D)) * sum_e Wq[d][e]K[c][e], d-split ------
__global__ __launch_bounds__(256) void prepB_kernel(
    const float* __restrict__ Wq, const float* __restrict__ Ktmp,
    unsigned short* __restrict__ MtP) {
  __shared__ float wqT[128][68];
  __shared__ float kt[32][129];
  const int bid = blockIdx.x;
  const int j = bid >> 4, ct = (bid >> 1) & 7, dh = bid & 1;
  const int tid = threadIdx.x;
  for (int i = tid; i < 64 * 32; i += 256) {
    int dloc = i >> 5, e4 = i & 31;
    float4 v = *(const float4*)(Wq + ((long)j * 128 + dh * 64 + dloc) * 128 + e4 * 4);
    wqT[e4 * 4 + 0][dloc] = v.x; wqT[e4 * 4 + 1][dloc] = v.y;
    wqT[e4 * 4 + 2][dloc] = v.z; wqT[e4 * 4 + 3][dloc] = v.w;
  }
  for (int i = tid; i < 32 * 32; i += 256) {
    int r = i >> 5, c0 = (i & 31) * 4;
    float4 v = *(const float4*)(Ktmp + ((long)j * 256 + ct * 32 + r) * 128 + c0);
    kt[r][c0 + 0] = v.x; kt[r][c0 + 1] = v.y;
    kt[r][c0 + 2] = v.z; kt[r][c0 + 3] = v.w;
  }
  __syncthreads();
  const int cl = tid >> 3, s = tid & 7;
  float acc[8];
#pragma unroll
  for (int u = 0; u < 8; ++u) acc[u] = 0.f;
  for (int e = 0; e < 128; ++e) {
    float kk = kt[cl][e];
    float4 a = *(const float4*)&wqT[e][s * 8];
    float4 b = *(const float4*)&wqT[e][s * 8 + 4];
    acc[0] = fmaf(a.x, kk, acc[0]); acc[1] = fmaf(a.y, kk, acc[1]);
    acc[2] = fmaf(a.z, kk, acc[2]); acc[3] = fmaf(a.w, kk, acc[3]);
    acc[4] = fmaf(b.x, kk, acc[4]); acc[5] = fmaf(b.y, kk, acc[5]);
    acc[6] = fmaf(b.z, kk, acc[6]); acc[7] = fmaf(b.w, kk, acc[7]);
  }
  const float scale = 0.08838834764831845f;  // 1/sqrt(128)
  int c = ct * 32 + cl;
  uint4 pk = {pk2(acc[0] * scale, acc[1] * scale),
              pk2(acc[2] * scale, acc[3] * scale),
              pk2(acc[4] * scale, acc[5] * scale),
              pk2(acc[6] * scale, acc[7] * scale)};
  int slot = dh * 8 + s;
  long byte = (long)j * 65536 + c * 256 + ((slot ^ (c & 7)) << 4);
  *(uint4*)((char*)MtP + byte) = pk;
}

// ---------------- fused main kernel (r6 verbatim) --------------------------
// LDS: wb 2x16KB panel quarters + sv 4KB params = 36KB -> 4 blocks/CU.
__global__ __launch_bounds__(256, 4) void fused_kernel(
    const float* __restrict__ x, const unsigned short* __restrict__ MtP,
    const unsigned short* __restrict__ VtP, const unsigned short* __restrict__ W1tP,
    const unsigned short* __restrict__ W2tP, const float* __restrict__ b1,
    const float* __restrict__ b2, const float* __restrict__ g1,
    const float* __restrict__ be1, const float* __restrict__ g2,
    const float* __restrict__ be2, const float* __restrict__ Ws,
    const float* __restrict__ bs, float* __restrict__ out) {
  __shared__ __align__(16) unsigned short wb[2][8192];
  __shared__ __align__(16) float sv[1024];
  const int bid = blockIdx.x;
  const int wg = (bid & 7) * 256 + (bid >> 3);  // XCD-chunked
  const int j = wg >> 6, b0 = (wg & 63) * 64;
  const int tid = threadIdx.x, w = tid >> 6, l = tid & 63, lr = l & 15, lg = l >> 4;
  const int bloc = w * 16 + lr;

  const unsigned short* pnl0 = MtP + (long)j * 32768;
  const unsigned short* pnl1 = VtP + (long)j * 32768;
  const unsigned short* pnl2 = W1tP + (long)j * 32768;
  const unsigned short* pnl3 = W2tP + (long)j * 32768;

  auto ISSUE = [&](int s2) {
    const unsigned short* base = (s2 < 4) ? pnl0 : (s2 < 8) ? pnl1 : (s2 < 12) ? pnl2 : pnl3;
    const char* gq = (const char*)(base + (s2 & 3) * 8192);
    char* lb = (char*)&wb[s2 & 1][0] + w * 4096;
    SB;
#pragma unroll
    for (int t = 0; t < 4; ++t)
      gload16(gq + (w * 4 + t) * 1024 + l * 16, lb + t * 1024);
    SB;
  };

  // ---- prologue ----
  const float* xrow = x + ((long)(b0 + bloc) * NC + j) * D;
  float4 xf[4][2];
#pragma unroll
  for (int kc = 0; kc < 4; ++kc) {
    xf[kc][0] = *(const float4*)(xrow + kc * 32 + lg * 8);
    xf[kc][1] = *(const float4*)(xrow + kc * 32 + lg * 8 + 4);
  }
  for (int i = tid; i < 1024; i += 256) {
    float v;
    if (i < 256) v = b1[j * H + i];
    else if (i < 384) v = b2[j * D + i - 256];
    else if (i < 512) v = g1[i - 384];
    else if (i < 640) v = be1[i - 512];
    else if (i < 768) v = g2[i - 640];
    else if (i < 896) v = be2[i - 768];
    else v = Ws[j * D + i - 896];
    sv[i] = v;
  }
  SB;
  ISSUE(0);
  ISSUE(1);
  float bsj = bs[j];
  bf16x8 xa[4];
#pragma unroll
  for (int kc = 0; kc < 4; ++kc) {
    u32x4 t;
    t[0] = cvtpk(xf[kc][0].x, xf[kc][0].y);
    t[1] = cvtpk(xf[kc][0].z, xf[kc][0].w);
    t[2] = cvtpk(xf[kc][1].x, xf[kc][1].y);
    t[3] = cvtpk(xf[kc][1].z, xf[kc][1].w);
    xa[kc] = __builtin_bit_cast(bf16x8, t);
  }
  lgkm0(); SB; BARR; MEMF; SB;

  int inner[4], inner2[8];
#pragma unroll
  for (int kc = 0; kc < 4; ++kc)
    inner[kc] = lr * 256 + (((kc * 4 + lg) ^ (lr & 7)) << 4);
#pragma unroll
  for (int kc = 0; kc < 8; ++kc)
    inner2[kc] = lr * 512 + (((kc * 4 + lg) ^ (lr & 7)) << 4);

  const int ad0 = (((lg & 1) << 5) + lr) << 2;  // bpermute byte addr, half 0
  const int ad1 = ad0 + 64;                     // half 1
  const bool hi = (lg >> 1) != 0;

  bf16x8 aa[8], xa2[4], aa2[8];
  unsigned hb[8][2];
  float4 xr[8];

  // ---- GEMM1: S^T = Mt @ x^T (stages 0..3) ----
  f32x4 sc[16];
#pragma unroll
  for (int t = 0; t < 16; ++t) sc[t] = (f32x4){0.f, 0.f, 0.f, 0.f};
#pragma unroll
  for (int q = 0; q < 4; ++q) {
    vmwait<4>(); SB; BARR; MEMF; SB;
    const char* wp = (const char*)wb[q & 1];
    __builtin_amdgcn_s_setprio(1);
#pragma unroll
    for (int c4 = 0; c4 < 4; ++c4)
#pragma unroll
      for (int kc = 0; kc < 4; ++kc) {
        bf16x8 bf = *(const bf16x8*)(wp + c4 * 4096 + inner[kc]);
        sc[q * 4 + c4] =
            __builtin_amdgcn_mfma_f32_16x16x32_bf16(bf, xa[kc], sc[q * 4 + c4], 0, 0, 0);
      }
    __builtin_amdgcn_s_setprio(0);
    if (q == 3) {
      float mx = -1e30f;
#pragma unroll
      for (int ct = 0; ct < 16; ++ct)
#pragma unroll
        for (int i = 0; i < 4; ++i) mx = fmaxf(mx, sc[ct][i]);
      mx = fmaxf(mx, __shfl_xor(mx, 16));
      mx = fmaxf(mx, __shfl_xor(mx, 32));
      float sm = 0.f;
#pragma unroll
      for (int ct = 0; ct < 16; ++ct)
#pragma unroll
        for (int i = 0; i < 4; ++i) {
          float e = __expf(sc[ct][i] - mx);
          sc[ct][i] = e;
          sm += e;
        }
      sm += __shfl_xor(sm, 16);
      sm += __shfl_xor(sm, 32);
      float inv = 1.f / sm;
      unsigned au[16][2];
#pragma unroll
      for (int ct = 0; ct < 16; ++ct) {
        au[ct][0] = cvtpk(sc[ct][0] * inv, sc[ct][1] * inv);
        au[ct][1] = cvtpk(sc[ct][2] * inv, sc[ct][3] * inv);
      }
#pragma unroll
      for (int kc = 0; kc < 8; ++kc) {
        u32x4 t;
#pragma unroll
        for (int h = 0; h < 2; ++h) {
          int ad = h ? ad1 : ad0;
#pragma unroll
          for (int p = 0; p < 2; ++p) {
            int f0 = __builtin_amdgcn_ds_bpermute(ad, (int)au[2 * kc][p]);
            int f1 = __builtin_amdgcn_ds_bpermute(ad, (int)au[2 * kc + 1][p]);
            t[h * 2 + p] = (unsigned)(hi ? f1 : f0);
          }
        }
        aa[kc] = __builtin_bit_cast(bf16x8, t);
      }
    }
    lgkm0(); SB; BARR; MEMF; SB;
    ISSUE(q + 2);
  }

  // ---- GEMM2: h^T = V^T @ alpha^T (stages 4..7) ----
  f32x4 ha[8];
#pragma unroll
  for (int t = 0; t < 8; ++t) ha[t] = (f32x4){0.f, 0.f, 0.f, 0.f};
#pragma unroll
  for (int q = 0; q < 4; ++q) {
    vmwait<4>(); SB; BARR; MEMF; SB;
    const char* wp = (const char*)wb[q & 1];
    __builtin_amdgcn_s_setprio(1);
#pragma unroll
    for (int e2 = 0; e2 < 2; ++e2)
#pragma unroll
      for (int kc = 0; kc < 8; ++kc) {
        bf16x8 bf = *(const bf16x8*)(wp + e2 * 8192 + inner2[kc]);
        ha[q * 2 + e2] =
            __builtin_amdgcn_mfma_f32_16x16x32_bf16(bf, aa[kc], ha[q * 2 + e2], 0, 0, 0);
      }
    __builtin_amdgcn_s_setprio(0);
    if (q == 2) {  // x-residual loads; drained by stage-7 vmwait<4>
#pragma unroll
      for (int et = 0; et < 8; ++et)
        xr[et] = *(const float4*)(xrow + et * 16 + lg * 4);
    }
    if (q == 3) {
      float hvv[8][4];
      float s1 = 0.f, s2s = 0.f;
#pragma unroll
      for (int et = 0; et < 8; ++et)
#pragma unroll
        for (int i = 0; i < 4; ++i) {
          float v = ha[et][i] + xr[et][i];
          hvv[et][i] = v;
          s1 += v;
          s2s += v * v;
        }
      s1 += __shfl_xor(s1, 16); s2s += __shfl_xor(s2s, 16);
      s1 += __shfl_xor(s1, 32); s2s += __shfl_xor(s2s, 32);
      float mu = s1 * (1.f / 128.f);
      float var = s2s * (1.f / 128.f) - mu * mu;
      float rs = rsqrtf(var + 1e-5f);
#pragma unroll
      for (int et = 0; et < 8; ++et) {
        f32x4 gg = *(const f32x4*)&sv[384 + et * 16 + lg * 4];
        f32x4 bb = *(const f32x4*)&sv[512 + et * 16 + lg * 4];
        float h0 = (hvv[et][0] - mu) * rs * gg[0] + bb[0];
        float h1n = (hvv[et][1] - mu) * rs * gg[1] + bb[1];
        float h2 = (hvv[et][2] - mu) * rs * gg[2] + bb[2];
        float h3 = (hvv[et][3] - mu) * rs * gg[3] + bb[3];
        hb[et][0] = cvtpk(h0, h1n);
        hb[et][1] = cvtpk(h2, h3);
      }
#pragma unroll
      for (int kc = 0; kc < 4; ++kc) {
        u32x4 t;
#pragma unroll
        for (int h = 0; h < 2; ++h) {
          int ad = h ? ad1 : ad0;
#pragma unroll
          for (int p = 0; p < 2; ++p) {
            int f0 = __builtin_amdgcn_ds_bpermute(ad, (int)hb[2 * kc][p]);
            int f1 = __builtin_amdgcn_ds_bpermute(ad, (int)hb[2 * kc + 1][p]);
            t[h * 2 + p] = (unsigned)(hi ? f1 : f0);
          }
        }
        xa2[kc] = __builtin_bit_cast(bf16x8, t);
      }
    }
    lgkm0(); SB; BARR; MEMF; SB;
    ISSUE(6 + q);
  }

  // ---- GEMM3: ff^T = W1^T @ h1^T (stages 8..11) ----
  unsigned ffu[16][2];
#pragma unroll
  for (int q = 0; q < 4; ++q) {
    vmwait<4>(); SB; BARR; MEMF; SB;
    const char* wp = (const char*)wb[q & 1];
    f32x4 fa4[4];
#pragma unroll
    for (int t = 0; t < 4; ++t) fa4[t] = (f32x4){0.f, 0.f, 0.f, 0.f};
    __builtin_amdgcn_s_setprio(1);
#pragma unroll
    for (int c4 = 0; c4 < 4; ++c4)
#pragma unroll
      for (int kc = 0; kc < 4; ++kc) {
        bf16x8 bf = *(const bf16x8*)(wp + c4 * 4096 + inner[kc]);
        fa4[c4] =
            __builtin_amdgcn_mfma_f32_16x16x32_bf16(bf, xa2[kc], fa4[c4], 0, 0, 0);
      }
    __builtin_amdgcn_s_setprio(0);
#pragma unroll
    for (int c4 = 0; c4 < 4; ++c4) {  // relu + b1, pack
      int ht = q * 4 + c4;
      f32x4 bb = *(const f32x4*)&sv[ht * 16 + lg * 4];
      float v0 = fmaxf(fa4[c4][0] + bb[0], 0.f);
      float v1 = fmaxf(fa4[c4][1] + bb[1], 0.f);
      float v2 = fmaxf(fa4[c4][2] + bb[2], 0.f);
      float v3 = fmaxf(fa4[c4][3] + bb[3], 0.f);
      ffu[ht][0] = cvtpk(v0, v1);
      ffu[ht][1] = cvtpk(v2, v3);
    }
    if (q == 3) {
#pragma unroll
      for (int kc = 0; kc < 8; ++kc) {
        u32x4 t;
#pragma unroll
        for (int h = 0; h < 2; ++h) {
          int ad = h ? ad1 : ad0;
#pragma unroll
          for (int p = 0; p < 2; ++p) {
            int f0 = __builtin_amdgcn_ds_bpermute(ad, (int)ffu[2 * kc][p]);
            int f1 = __builtin_amdgcn_ds_bpermute(ad, (int)ffu[2 * kc + 1][p]);
            t[h * 2 + p] = (unsigned)(hi ? f1 : f0);
          }
        }
        aa2[kc] = __builtin_bit_cast(bf16x8, t);
      }
    }
    lgkm0(); SB; BARR; MEMF; SB;
    ISSUE(10 + q);
  }

  // ---- GEMM4: o^T = W2^T @ ff^T (stages 12..15) ----
  f32x4 oa[8];
#pragma unroll
  for (int t = 0; t < 8; ++t) oa[t] = (f32x4){0.f, 0.f, 0.f, 0.f};
#pragma unroll
  for (int q = 0; q < 4; ++q) {
    if (q == 3) { vmwait<0>(); } else { vmwait<4>(); }
    SB; BARR; MEMF; SB;
    const char* wp = (const char*)wb[q & 1];
    __builtin_amdgcn_s_setprio(1);
#pragma unroll
    for (int e2 = 0; e2 < 2; ++e2)
#pragma unroll
      for (int kc = 0; kc < 8; ++kc) {
        bf16x8 bf = *(const bf16x8*)(wp + e2 * 8192 + inner2[kc]);
        oa[q * 2 + e2] =
            __builtin_amdgcn_mfma_f32_16x16x32_bf16(bf, aa2[kc], oa[q * 2 + e2], 0, 0, 0);
      }
    __builtin_amdgcn_s_setprio(0);
    if (q < 3) {
      lgkm0(); SB; BARR; MEMF; SB;
      if (q < 2) ISSUE(14 + q);
    }
  }
  // final epilogue: +b2 +h1(bf16), LN2, dot Ws, sigmoid
  {
    float t1 = 0.f, t2 = 0.f;
#pragma unroll
    for (int et = 0; et < 8; ++et) {
      f32x4 bb = *(const f32x4*)&sv[256 + et * 16 + lg * 4];
      float r0 = b2f((unsigned short)(hb[et][0] & 0xffff));
      float r1 = b2f((unsigned short)(hb[et][0] >> 16));
      float r2 = b2f((unsigned short)(hb[et][1] & 0xffff));
      float r3 = b2f((unsigned short)(hb[et][1] >> 16));
      float v0 = oa[et][0] + bb[0] + r0;
      float v1 = oa[et][1] + bb[1] + r1;
      float v2 = oa[et][2] + bb[2] + r2;
      float v3 = oa[et][3] + bb[3] + r3;
      oa[et][0] = v0; oa[et][1] = v1; oa[et][2] = v2; oa[et][3] = v3;
      t1 += (v0 + v1) + (v2 + v3);
      t2 += (v0 * v0 + v1 * v1) + (v2 * v2 + v3 * v3);
    }
    t1 += __shfl_xor(t1, 16); t2 += __shfl_xor(t2, 16);
    t1 += __shfl_xor(t1, 32); t2 += __shfl_xor(t2, 32);
    float mu2 = t1 * (1.f / 128.f);
    float var = t2 * (1.f / 128.f) - mu2 * mu2;
    float rs2 = rsqrtf(var + 1e-5f);
    float lp = 0.f;
#pragma unroll
    for (int et = 0; et < 8; ++et) {
      f32x4 gg = *(const f32x4*)&sv[640 + et * 16 + lg * 4];
      f32x4 bb = *(const f32x4*)&sv[768 + et * 16 + lg * 4];
      f32x4 ww = *(const f32x4*)&sv[896 + et * 16 + lg * 4];
#pragma unroll
      for (int i = 0; i < 4; ++i) {
        float h2 = (oa[et][i] - mu2) * rs2 * gg[i] + bb[i];
        lp = fmaf(h2, ww[i], lp);
      }
    }
    lp += __shfl_xor(lp, 16);
    lp += __shfl_xor(lp, 32);
    if (lg == 0) {
      float sg = 1.f / (1.f + __expf(-(lp + bsj)));
      out[(long)(b0 + bloc) * NC + j] = sg;
    }
  }
}

extern "C" void kernel_launch(void* const* d_in, const int* in_sizes, int n_in,
                              void* d_out, int out_size, void* d_ws,
                              size_t ws_size, hipStream_t stream) {
  (void)in_sizes; (void)n_in; (void)out_size; (void)ws_size;
  const float* cat = (const float*)d_in[1];
  const float* emb = (const float*)d_in[2];
  const float* Wq = (const float*)d_in[3];
  const float* Wk = (const float*)d_in[4];
  const float* Wv = (const float*)d_in[5];
  const float* g1 = (const float*)d_in[6];
  const float* be1 = (const float*)d_in[7];
  const float* W1 = (const float*)d_in[8];
  const float* b1 = (const float*)d_in[9];
  const float* W2 = (const float*)d_in[10];
  const float* b2 = (const float*)d_in[11];
  const float* g2 = (const float*)d_in[12];
  const float* be2 = (const float*)d_in[13];
  const float* Ws = (const float*)d_in[14];
  const float* bs = (const float*)d_in[15];
  float* out = (float*)d_out;

  // workspace: 12 MB
  char* ws = (char*)d_ws;
  unsigned short* MtP = (unsigned short*)(ws);              // 2 MB swz [NC][256][128]
  unsigned short* VtP = (unsigned short*)(ws + (2 << 20));  // 2 MB swz [NC][128][256]
  unsigned short* W1tP = (unsigned short*)(ws + (4 << 20)); // 2 MB swz [NC][256][128]
  unsigned short* W2tP = (unsigned short*)(ws + (6 << 20)); // 2 MB swz [NC][128][256]
  float* Ktmp = (float*)(ws + (8 << 20));                   // 4 MB [NC][256][128]

  prepA_kernel<<<2560, 256, 0, stream>>>(emb, Wk, Wv, W1, W2, Ktmp, VtP, W1tP, W2tP);
  prepB_kernel<<<512, 256, 0, stream>>>(Wq, Ktmp, MtP);
  fused_kernel<<<2048, 256, 0, stream>>>(cat, MtP, VtP, W1tP, W2tP, b1, b2, g1,
                                         be1, g2, be2, Ws, bs, out);
}